// Round 7
// baseline (1169.879 us; speedup 1.0000x reference)
//
#include <hip/hip_runtime.h>

typedef __attribute__((ext_vector_type(8))) __bf16 bf16x8;
typedef __attribute__((ext_vector_type(4))) __bf16 bf16x4;
typedef __attribute__((ext_vector_type(4))) float f32x4;
typedef __attribute__((ext_vector_type(16))) float f32x16;

#define SEQ   4096
#define NIN   1024
#define DH    128
#define NOUTD 1024
#define HEADS 8
#define CPH   1280
#define L2E   1.44269504f
#define KTOT  32768   // concat K for PV GEMM = HEADS*SEQ

static __device__ inline f32x16 zero16() {
  f32x16 z;
#pragma unroll
  for (int r = 0; r < 16; ++r) z[r] = 0.f;
  return z;
}

static __device__ inline unsigned pk2(float a, float b) {
  unsigned short ua = __builtin_bit_cast(unsigned short, (__bf16)a);
  unsigned short ub = __builtin_bit_cast(unsigned short, (__bf16)b);
  return (unsigned)ua | ((unsigned)ub << 16);
}

// ---------------------------------------------------------------- f32 -> bf16
__global__ __launch_bounds__(256) void k_cvt(const float* __restrict__ src,
                                             __bf16* __restrict__ dst, int n) {
  int i = (blockIdx.x * 256 + threadIdx.x) * 4;
  if (i >= n) return;
  float4 v = *(const float4*)(src + i);
  bf16x4 o = { (__bf16)v.x, (__bf16)v.y, (__bf16)v.z, (__bf16)v.w };
  *(bf16x4*)(dst + i) = o;
}

// ---------------------------------------------------------------- zero d_out
__global__ __launch_bounds__(256) void k_zero(float4* __restrict__ p) {
  p[(size_t)blockIdx.x * 256 + threadIdx.x] = float4{0.f, 0.f, 0.f, 0.f};
}

// ------------------------------------------- GEMM: out = x @ W^T + b, scatter
// Kx[h][i][d] pre-scaled; Q2[h][dg][j][8].
// vmode=0: V2[h][J][e][8]   (fused-attn fallback layout)
// vmode=1: VT[e][h*SEQ + j] (B^T layout for the PV GEMM)
__global__ __launch_bounds__(256) void k_gemm_qkv(
    const __bf16* __restrict__ xb, const __bf16* __restrict__ wb,
    const float* __restrict__ bias,
    __bf16* __restrict__ Kx, __bf16* __restrict__ Q2, __bf16* __restrict__ Vd,
    int vmode)
{
  __shared__ __align__(16) __bf16 As[128 * 32];
  __shared__ __align__(16) __bf16 Bs[128 * 32];
  const int tid = threadIdx.x;
  const int w = tid >> 6, l = tid & 63;
  const int i0 = blockIdx.x * 128;
  const int n0 = blockIdx.y * 128;
  const int lrow = l & 15;
  const int lkb  = (l >> 4) * 16;
  const int soff = (w * 2) * 1024 + l * 16;

  f32x4 acc[4][4] = {};

  for (int kt = 0; kt < 32; ++kt) {
    __syncthreads();
#pragma unroll
    for (int q = 0; q < 2; ++q) {
      int off = soff + q * 1024;
      int row = off >> 6, kb = off & 63;
      const __bf16* ga = xb + (size_t)(i0 + row) * NIN + kt * 32 + (kb >> 1);
      const __bf16* gb = wb + (size_t)(n0 + row) * NIN + kt * 32 + (kb >> 1);
      __builtin_amdgcn_global_load_lds(
          (const __attribute__((address_space(1))) void*)ga,
          (__attribute__((address_space(3))) void*)((char*)As + (w * 2 + q) * 1024),
          16, 0, 0);
      __builtin_amdgcn_global_load_lds(
          (const __attribute__((address_space(1))) void*)gb,
          (__attribute__((address_space(3))) void*)((char*)Bs + (w * 2 + q) * 1024),
          16, 0, 0);
    }
    __syncthreads();
    bf16x8 af[4], bfr[4];
#pragma unroll
    for (int mi = 0; mi < 4; ++mi)
      af[mi] = *(const bf16x8*)((const char*)As + (((w >> 1) * 64 + mi * 16 + lrow) * 64) + lkb);
#pragma unroll
    for (int ni = 0; ni < 4; ++ni)
      bfr[ni] = *(const bf16x8*)((const char*)Bs + (((w & 1) * 64 + ni * 16 + lrow) * 64) + lkb);
#pragma unroll
    for (int mi = 0; mi < 4; ++mi)
#pragma unroll
      for (int ni = 0; ni < 4; ++ni)
        acc[mi][ni] = __builtin_amdgcn_mfma_f32_16x16x32_bf16(af[mi], bfr[ni], acc[mi][ni], 0, 0, 0);
  }

  const int iw = i0 + (w >> 1) * 64;
  const int nw = n0 + (w & 1) * 64;
  const int lhi = l >> 4;
#pragma unroll
  for (int ni = 0; ni < 4; ++ni) {
    int n = nw + ni * 16 + lrow;
    float bv = bias[n];
    int h = n / CPH;
    int c = n - h * CPH;
    if (c < 128) {
#pragma unroll
      for (int mi = 0; mi < 4; ++mi)
#pragma unroll
        for (int r = 0; r < 4; ++r) {
          int i = iw + mi * 16 + lhi * 4 + r;
          float v = acc[mi][ni][r] + bv;
          Kx[(((size_t)h * SEQ + i) << 7) + c] = (__bf16)(v * 0.08838834764831845f);
        }
    } else if (c < 256) {
      int d = c - 128;
      size_t qEl = ((size_t)(h * 16 + (d >> 3)) << 15) + (size_t)(d & 7);
#pragma unroll
      for (int mi = 0; mi < 4; ++mi)
#pragma unroll
        for (int r = 0; r < 4; ++r) {
          int j = iw + mi * 16 + lhi * 4 + r;
          Q2[qEl + ((size_t)j << 3)] = (__bf16)(acc[mi][ni][r] + bv);
        }
    } else {
      int e = c - 256;
#pragma unroll
      for (int mi = 0; mi < 4; ++mi) {
        int jb = iw + mi * 16 + lhi * 4;
        bf16x4 pk = { (__bf16)(acc[mi][ni][0] + bv), (__bf16)(acc[mi][ni][1] + bv),
                      (__bf16)(acc[mi][ni][2] + bv), (__bf16)(acc[mi][ni][3] + bv) };
        if (vmode) {
          *(bf16x4*)(Vd + (size_t)e * KTOT + (size_t)h * SEQ + jb) = pk;
        } else {
          int J = jb >> 3, js = jb & 7;
          *(bf16x4*)(Vd + (((size_t)(h * 512 + J)) << 13) + ((size_t)e << 3) + js) = pk;
        }
      }
    }
  }
}

// --------------------------------------------------------- pass A: softmax stats
// grid 256 = h(8) x itile(32 of 128 rows). 256 thr, 4 waves x 32 i-rows.
__global__ __launch_bounds__(256) void k_stats(
    const __bf16* __restrict__ Kx, const __bf16* __restrict__ Q2,
    float* __restrict__ stat_m, float* __restrict__ stat_il)
{
  __shared__ __align__(16) char Qb[2][16384];
  const int tid = threadIdx.x;
  const int w = tid >> 6, l = tid & 63;
  const int l31 = l & 31, hl = l >> 5;
  const int b = blockIdx.x;
  const int h = b >> 5;
  const int i_base = (b & 31) * 128;
  const __bf16* Kh = Kx + ((size_t)h * SEQ << 7);
  const char* q2b = (const char*)Q2 + ((size_t)h << 20);

  bf16x8 kf[8];
#pragma unroll
  for (int c = 0; c < 8; ++c)
    kf[c] = *(const bf16x8*)(Kh + (((size_t)(i_base + 32 * w + l31)) << 7) + c * 16 + hl * 8);

  float m_run = -1e30f, l_run = 0.f;

#pragma unroll
  for (int k = 0; k < 4; ++k) {
    int s = tid + k * 256;
    const char* src = q2b + ((size_t)(s >> 6) << 16) + (size_t)(s & 63) * 16;
    __builtin_amdgcn_global_load_lds(
        (const __attribute__((address_space(1))) void*)src,
        (__attribute__((address_space(3))) void*)(Qb[0] + s * 16), 16, 0, 0);
  }
  __syncthreads();

  for (int jt = 0; jt < 64; ++jt) {
    const int cur = jt & 1;
    if (jt < 63) {
      int j0n = (jt + 1) * 64;
#pragma unroll
      for (int k = 0; k < 4; ++k) {
        int s = tid + k * 256;
        const char* src = q2b + ((size_t)(s >> 6) << 16) + (size_t)(j0n + (s & 63)) * 16;
        __builtin_amdgcn_global_load_lds(
            (const __attribute__((address_space(1))) void*)src,
            (__attribute__((address_space(3))) void*)(Qb[cur ^ 1] + s * 16), 16, 0, 0);
      }
    }
    const char* qb = Qb[cur];

    f32x16 s0 = zero16(), s1 = zero16();
#pragma unroll
    for (int c = 0; c < 8; ++c) {
      bf16x8 a0 = *(const bf16x8*)(qb + (((2 * c + hl) * 64 + l31) << 4));
      bf16x8 a1 = *(const bf16x8*)(qb + (((2 * c + hl) * 64 + 32 + l31) << 4));
      s0 = __builtin_amdgcn_mfma_f32_32x32x16_bf16(a0, kf[c], s0, 0, 0, 0);
      s1 = __builtin_amdgcn_mfma_f32_32x32x16_bf16(a1, kf[c], s1, 0, 0, 0);
    }

    float pm = -1e30f;
#pragma unroll
    for (int r = 0; r < 16; ++r) pm = fmaxf(pm, fmaxf(s0[r], s1[r]));
    float mn = fmaxf(m_run, pm);
    l_run *= exp2f((m_run - mn) * L2E);
    float a = 0.f;
#pragma unroll
    for (int r = 0; r < 16; ++r)
      a += exp2f((s0[r] - mn) * L2E) + exp2f((s1[r] - mn) * L2E);
    l_run += a;
    m_run = mn;
    __syncthreads();
  }

  float mp = __shfl_xor(m_run, 32);
  float lp = __shfl_xor(l_run, 32);
  float mf = fmaxf(m_run, mp);
  float lf = l_run * exp2f((m_run - mf) * L2E) + lp * exp2f((mp - mf) * L2E);
  if (hl == 0) {
    int i = i_base + 32 * w + l31;
    stat_m[h * SEQ + i] = mf;
    stat_il[h * SEQ + i] = 1.0f / lf;
  }
}

// --------------------------------------------------------- P~ write pass (chunked)
// Recompute S for heads [h0, h0+nh), rows [i0, i0+nit*128), j-slice per block.
// P chunk layout: P[i_loc][hh*SEQ + j], row stride ldP = nh*SEQ.
// grid = nh * nit * njs;  b -> js (fastest), itile, hh.
__global__ __launch_bounds__(256) void k_pwrite(
    const __bf16* __restrict__ Kx, const __bf16* __restrict__ Q2,
    const float* __restrict__ stat_m, const float* __restrict__ stat_il,
    __bf16* __restrict__ P, int h0, int i0, int nit, int njs, int njt, int ldP)
{
  __shared__ __align__(16) char Qb[2][16384];
  const int tid = threadIdx.x;
  const int w = tid >> 6, l = tid & 63;
  const int l31 = l & 31, hl = l >> 5;

  const int bb = blockIdx.x;
  const int js = bb % njs;
  const int rem = bb / njs;
  const int itile = rem % nit;
  const int hh = rem / nit;
  const int h = h0 + hh;
  const int jt0 = js * njt;

  const __bf16* Kh = Kx + ((size_t)h * SEQ << 7);
  const char* q2b = (const char*)Q2 + ((size_t)h << 20);

  const int i_loc = itile * 128 + 32 * w + l31;
  const int i_gl = i0 + i_loc;
  const float m_i = stat_m[h * SEQ + i_gl];
  const float il_i = stat_il[h * SEQ + i_gl];
  __bf16* prow = P + (size_t)i_loc * ldP + (size_t)hh * SEQ;

  bf16x8 kf[8];
#pragma unroll
  for (int c = 0; c < 8; ++c)
    kf[c] = *(const bf16x8*)(Kh + (((size_t)i_gl) << 7) + c * 16 + hl * 8);

#pragma unroll
  for (int k = 0; k < 4; ++k) {
    int s = tid + k * 256;
    const char* src = q2b + ((size_t)(s >> 6) << 16) + (size_t)(jt0 * 64 + (s & 63)) * 16;
    __builtin_amdgcn_global_load_lds(
        (const __attribute__((address_space(1))) void*)src,
        (__attribute__((address_space(3))) void*)(Qb[0] + s * 16), 16, 0, 0);
  }
  __syncthreads();

  for (int t = 0; t < njt; ++t) {
    const int jt = jt0 + t;
    const int cur = t & 1;
    if (t < njt - 1) {
      int j0n = (jt + 1) * 64;
#pragma unroll
      for (int k = 0; k < 4; ++k) {
        int s = tid + k * 256;
        const char* src = q2b + ((size_t)(s >> 6) << 16) + (size_t)(j0n + (s & 63)) * 16;
        __builtin_amdgcn_global_load_lds(
            (const __attribute__((address_space(1))) void*)src,
            (__attribute__((address_space(3))) void*)(Qb[cur ^ 1] + s * 16), 16, 0, 0);
      }
    }
    const char* qb = Qb[cur];

    f32x16 s0 = zero16(), s1 = zero16();
#pragma unroll
    for (int c = 0; c < 8; ++c) {
      bf16x8 a0 = *(const bf16x8*)(qb + (((2 * c + hl) * 64 + l31) << 4));
      bf16x8 a1 = *(const bf16x8*)(qb + (((2 * c + hl) * 64 + 32 + l31) << 4));
      s0 = __builtin_amdgcn_mfma_f32_32x32x16_bf16(a0, kf[c], s0, 0, 0, 0);
      s1 = __builtin_amdgcn_mfma_f32_32x32x16_bf16(a1, kf[c], s1, 0, 0, 0);
    }

    // transpose to row-contiguous j, fold il, store 16B per lane
#pragma unroll
    for (int c2 = 0; c2 < 4; ++c2) {
      const f32x16& sv = (c2 >> 1) ? s1 : s0;
      const int base = (c2 & 1) * 8;
      float e0 = il_i * exp2f((sv[base + 0] - m_i) * L2E);
      float e1 = il_i * exp2f((sv[base + 1] - m_i) * L2E);
      float e2 = il_i * exp2f((sv[base + 2] - m_i) * L2E);
      float e3 = il_i * exp2f((sv[base + 3] - m_i) * L2E);
      float e4 = il_i * exp2f((sv[base + 4] - m_i) * L2E);
      float e5 = il_i * exp2f((sv[base + 5] - m_i) * L2E);
      float e6 = il_i * exp2f((sv[base + 6] - m_i) * L2E);
      float e7 = il_i * exp2f((sv[base + 7] - m_i) * L2E);
      unsigned WA0 = pk2(e0, e1), WA1 = pk2(e2, e3);
      unsigned WB0 = pk2(e4, e5), WB1 = pk2(e6, e7);
      unsigned send0 = hl ? WA0 : WB0;
      unsigned send1 = hl ? WA1 : WB1;
      unsigned r0 = (unsigned)__shfl_xor((int)send0, 32);
      unsigned r1 = (unsigned)__shfl_xor((int)send1, 32);
      int4 qd;
      qd.x = (int)(hl ? r0 : WA0);
      qd.y = (int)(hl ? r1 : WA1);
      qd.z = (int)(hl ? WB0 : r0);
      qd.w = (int)(hl ? WB1 : r1);
      *(int4*)(prow + jt * 64 + 16 * c2 + 8 * hl) = qd;
    }
    __syncthreads();
  }
}

// --------------------------------------------------------- PV dense GEMM (chunked)
// out[i0+.., :] (+)= P_chunk[mr x ldP] @ VT[:, k0 + 0..ldP]^T
__global__ __launch_bounds__(256) void k_pv_gemm(
    const __bf16* __restrict__ P, const __bf16* __restrict__ VT,
    float* __restrict__ out, int ldP, int k0, int kiters, int i0, int beta)
{
  __shared__ __align__(16) __bf16 As[128 * 32];
  __shared__ __align__(16) __bf16 Bs[128 * 32];
  const int tid = threadIdx.x;
  const int w = tid >> 6, l = tid & 63;
  const int iblk = blockIdx.y * 128;
  const int n0 = blockIdx.x * 128;
  const int lrow = l & 15;
  const int lkb  = (l >> 4) * 16;
  const int soff = (w * 2) * 1024 + l * 16;

  f32x4 acc[4][4] = {};

  for (int kt = 0; kt < kiters; ++kt) {
    __syncthreads();
#pragma unroll
    for (int q = 0; q < 2; ++q) {
      int off = soff + q * 1024;
      int row = off >> 6, kb = off & 63;
      const __bf16* ga = P  + (size_t)(iblk + row) * ldP + kt * 32 + (kb >> 1);
      const __bf16* gb = VT + (size_t)(n0 + row) * KTOT + k0 + kt * 32 + (kb >> 1);
      __builtin_amdgcn_global_load_lds(
          (const __attribute__((address_space(1))) void*)ga,
          (__attribute__((address_space(3))) void*)((char*)As + (w * 2 + q) * 1024),
          16, 0, 0);
      __builtin_amdgcn_global_load_lds(
          (const __attribute__((address_space(1))) void*)gb,
          (__attribute__((address_space(3))) void*)((char*)Bs + (w * 2 + q) * 1024),
          16, 0, 0);
    }
    __syncthreads();
    bf16x8 af[4], bfr[4];
#pragma unroll
    for (int mi = 0; mi < 4; ++mi)
      af[mi] = *(const bf16x8*)((const char*)As + (((w >> 1) * 64 + mi * 16 + lrow) * 64) + lkb);
#pragma unroll
    for (int ni = 0; ni < 4; ++ni)
      bfr[ni] = *(const bf16x8*)((const char*)Bs + (((w & 1) * 64 + ni * 16 + lrow) * 64) + lkb);
#pragma unroll
    for (int mi = 0; mi < 4; ++mi)
#pragma unroll
      for (int ni = 0; ni < 4; ++ni)
        acc[mi][ni] = __builtin_amdgcn_mfma_f32_16x16x32_bf16(af[mi], bfr[ni], acc[mi][ni], 0, 0, 0);
  }

  const int iw = i0 + iblk + (w >> 1) * 64;
  const int nw = n0 + (w & 1) * 64;
  const int lhi = l >> 4;
  if (beta) {
#pragma unroll
    for (int ni = 0; ni < 4; ++ni) {
      int e = nw + ni * 16 + lrow;
#pragma unroll
      for (int mi = 0; mi < 4; ++mi)
#pragma unroll
        for (int r = 0; r < 4; ++r) {
          int i = iw + mi * 16 + lhi * 4 + r;
          out[((size_t)i << 10) + e] += acc[mi][ni][r];
        }
    }
  } else {
#pragma unroll
    for (int ni = 0; ni < 4; ++ni) {
      int e = nw + ni * 16 + lrow;
#pragma unroll
      for (int mi = 0; mi < 4; ++mi)
#pragma unroll
        for (int r = 0; r < 4; ++r) {
          int i = iw + mi * 16 + lhi * 4 + r;
          out[((size_t)i << 10) + e] = acc[mi][ni][r];
        }
    }
  }
}

// --------------------------------------------------------- fallback fused attn
__global__ __launch_bounds__(512, 2) void k_attn3(
    const __bf16* __restrict__ Kx, const __bf16* __restrict__ Q2,
    const __bf16* __restrict__ V2, const float* __restrict__ stat_m,
    const float* __restrict__ stat_il, float* __restrict__ out)
{
  __shared__ __align__(16) char Qb[2][8192];
  __shared__ __align__(16) char Vb[2][16384];
  __shared__ float s_linv[256];

  const int tid = threadIdx.x;
  const int w = tid >> 6, l = tid & 63;
  const int l31 = l & 31, hl = l >> 5;
  const int islot = w & 3, eslot = w >> 2;

  const int b = blockIdx.x;
  const int et = b & 3;
  const int h = ((b >> 2) & 1) + 2 * (b >> 7);
  const int it = (b >> 3) & 15;
  const int i_base = it * 256, e_base = et * 256;

  const __bf16* Kh = Kx + ((size_t)h * SEQ << 7);
  const char* q2b = (const char*)Q2 + ((size_t)h << 20);
  const char* v2b = (const char*)V2 + ((size_t)(h * 512) << 14) + ((size_t)e_base << 4);

  if (tid < 256) s_linv[tid] = stat_il[h * SEQ + i_base + tid];
  const int iw0 = i_base + islot * 64;
  const float m0 = stat_m[h * SEQ + iw0 + l31];
  const float m1 = stat_m[h * SEQ + iw0 + 32 + l31];

  bf16x8 kf[2][8];
#pragma unroll
  for (int ig = 0; ig < 2; ++ig)
#pragma unroll
    for (int c = 0; c < 8; ++c)
      kf[ig][c] = *(const bf16x8*)(Kh + (((size_t)(iw0 + ig * 32 + l31)) << 7) + c * 16 + hl * 8);

  f32x16 acc[2][4];
#pragma unroll
  for (int ig = 0; ig < 2; ++ig)
#pragma unroll
    for (int n = 0; n < 4; ++n) acc[ig][n] = zero16();

  {
    const char* srcQ = q2b + ((size_t)(tid >> 5) << 16) + (size_t)(tid & 31) * 16;
    __builtin_amdgcn_global_load_lds(
        (const __attribute__((address_space(1))) void*)srcQ,
        (__attribute__((address_space(3))) void*)(Qb[0] + tid * 16), 16, 0, 0);
#pragma unroll
    for (int k = 0; k < 2; ++k) {
      int s = tid + k * 512;
      const char* srcV = v2b + ((size_t)(s >> 8) << 14) + (size_t)(s & 255) * 16;
      __builtin_amdgcn_global_load_lds(
          (const __attribute__((address_space(1))) void*)srcV,
          (__attribute__((address_space(3))) void*)(Vb[0] + s * 16), 16, 0, 0);
    }
  }
  __syncthreads();

  for (int jt = 0; jt < 128; ++jt) {
    const int cur = jt & 1;
    if (jt < 127) {
      const int j0n = (jt + 1) * 32;
      const char* srcQ = q2b + ((size_t)(tid >> 5) << 16) + (size_t)(j0n + (tid & 31)) * 16;
      __builtin_amdgcn_global_load_lds(
          (const __attribute__((address_space(1))) void*)srcQ,
          (__attribute__((address_space(3))) void*)(Qb[cur ^ 1] + tid * 16), 16, 0, 0);
#pragma unroll
      for (int k = 0; k < 2; ++k) {
        int s = tid + k * 512;
        const char* srcV = v2b + ((size_t)((jt + 1) * 4 + (s >> 8)) << 14) + (size_t)(s & 255) * 16;
        __builtin_amdgcn_global_load_lds(
            (const __attribute__((address_space(1))) void*)srcV,
            (__attribute__((address_space(3))) void*)(Vb[cur ^ 1] + s * 16), 16, 0, 0);
      }
    }
    const char* qb = Qb[cur];
    const char* vb = Vb[cur];

    f32x16 s0 = zero16(), s1 = zero16();
#pragma unroll
    for (int c = 0; c < 8; ++c) {
      bf16x8 a0 = *(const bf16x8*)(qb + (((2 * c + hl) * 32 + l31) << 4));
      s0 = __builtin_amdgcn_mfma_f32_32x32x16_bf16(a0, kf[0][c], s0, 0, 0, 0);
      s1 = __builtin_amdgcn_mfma_f32_32x32x16_bf16(a0, kf[1][c], s1, 0, 0, 0);
    }

    bf16x8 pf[2][2];
#pragma unroll
    for (int ig = 0; ig < 2; ++ig) {
      const f32x16& sv = ig ? s1 : s0;
      const float mi = ig ? m1 : m0;
#pragma unroll
      for (int c2 = 0; c2 < 2; ++c2) {
        const int base = 8 * c2;
        float e0 = exp2f((sv[base + 0] - mi) * L2E);
        float e1 = exp2f((sv[base + 1] - mi) * L2E);
        float e2 = exp2f((sv[base + 2] - mi) * L2E);
        float e3 = exp2f((sv[base + 3] - mi) * L2E);
        float e4 = exp2f((sv[base + 4] - mi) * L2E);
        float e5 = exp2f((sv[base + 5] - mi) * L2E);
        float e6 = exp2f((sv[base + 6] - mi) * L2E);
        float e7 = exp2f((sv[base + 7] - mi) * L2E);
        unsigned WA0 = pk2(e0, e1), WA1 = pk2(e2, e3);
        unsigned WB0 = pk2(e4, e5), WB1 = pk2(e6, e7);
        unsigned send0 = hl ? WA0 : WB0;
        unsigned send1 = hl ? WA1 : WB1;
        unsigned r0 = (unsigned)__shfl_xor((int)send0, 32);
        unsigned r1 = (unsigned)__shfl_xor((int)send1, 32);
        int4 qd;
        qd.x = (int)(hl ? r0 : WA0);
        qd.y = (int)(hl ? r1 : WA1);
        qd.z = (int)(hl ? WB0 : r0);
        qd.w = (int)(hl ? WB1 : r1);
        pf[ig][c2] = __builtin_bit_cast(bf16x8, qd);
      }
    }

#pragma unroll
    for (int c2 = 0; c2 < 2; ++c2)
#pragma unroll
      for (int n = 0; n < 4; ++n) {
        bf16x8 bv = *(const bf16x8*)(vb + (((2 * c2 + hl) * 256 + eslot * 128 + 32 * n + l31) << 4));
        acc[0][n] = __builtin_amdgcn_mfma_f32_32x32x16_bf16(pf[0][c2], bv, acc[0][n], 0, 0, 0);
        acc[1][n] = __builtin_amdgcn_mfma_f32_32x32x16_bf16(pf[1][c2], bv, acc[1][n], 0, 0, 0);
      }
    __syncthreads();
  }

#pragma unroll
  for (int ig = 0; ig < 2; ++ig)
#pragma unroll
    for (int n = 0; n < 4; ++n) {
      const int e = e_base + eslot * 128 + 32 * n + l31;
#pragma unroll
      for (int r = 0; r < 16; ++r) {
        int row = (r & 3) + 8 * (r >> 2) + 4 * hl;
        int iloc = islot * 64 + ig * 32 + row;
        float v = acc[ig][n][r] * s_linv[iloc];
        atomicAdd(out + (((size_t)(i_base + iloc)) << 10) + e, v);
      }
    }
}

// ---------------------------------------------------------------- LayerNorm
__global__ __launch_bounds__(256) void k_ln(float* __restrict__ io,
                                            const float* __restrict__ lw,
                                            const float* __restrict__ lb) {
  const int i = blockIdx.x, t = threadIdx.x;
  const int w = t >> 6, l = t & 63;
  float4 v = *(const float4*)(io + ((size_t)i << 10) + t * 4);
  float s = v.x + v.y + v.z + v.w;
  float q = v.x * v.x + v.y * v.y + v.z * v.z + v.w * v.w;
#pragma unroll
  for (int d = 1; d < 64; d <<= 1) {
    s += __shfl_xor(s, d);
    q += __shfl_xor(q, d);
  }
  __shared__ float red[4][2];
  if (l == 0) { red[w][0] = s; red[w][1] = q; }
  __syncthreads();
  s = red[0][0] + red[1][0] + red[2][0] + red[3][0];
  q = red[0][1] + red[1][1] + red[2][1] + red[3][1];
  float mean = s * (1.0f / 1024.0f);
  float var = q * (1.0f / 1024.0f) - mean * mean;
  float rstd = rsqrtf(var + 1e-5f);
  float4 gw = *(const float4*)(lw + t * 4);
  float4 gb = *(const float4*)(lb + t * 4);
  float4 ov;
  ov.x = (v.x - mean) * rstd * gw.x + gb.x;
  ov.y = (v.y - mean) * rstd * gw.y + gb.y;
  ov.z = (v.z - mean) * rstd * gw.z + gb.z;
  ov.w = (v.w - mean) * rstd * gw.w + gb.w;
  *(float4*)(io + ((size_t)i << 10) + t * 4) = ov;
}

// ---------------------------------------------------------------- launch
extern "C" void kernel_launch(void* const* d_in, const int* in_sizes, int n_in,
                              void* d_out, int out_size, void* d_ws, size_t ws_size,
                              hipStream_t stream) {
  (void)in_sizes; (void)n_in; (void)out_size;
  const float* x  = (const float*)d_in[0];
  const float* W  = (const float*)d_in[1];
  const float* b  = (const float*)d_in[2];
  const float* lw = (const float*)d_in[3];
  const float* lb = (const float*)d_in[4];
  float* out = (float*)d_out;
  char* ws = (char*)d_ws;

  __bf16* xb = (__bf16*)ws;                                    //  8 MB (dead after GEMM)
  __bf16* wb = (__bf16*)(ws + (size_t)8  * 1024 * 1024);       // 20 MB
  __bf16* Kx = (__bf16*)(ws + (size_t)28 * 1024 * 1024);       //  8 MB
  __bf16* Q2 = (__bf16*)(ws + (size_t)36 * 1024 * 1024);       //  8 MB
  __bf16* Vd = (__bf16*)(ws + (size_t)44 * 1024 * 1024);       // 64 MB (V2 or VT)
  __bf16* P  = (__bf16*)(ws + (size_t)108 * 1024 * 1024);      // chunk buffer
  float* stat_m  = (float*)ws;                                 // reuse xb after GEMM
  float* stat_il = (float*)(ws + (size_t)128 * 1024);

  const size_t MB = (size_t)1024 * 1024;
  const size_t avail = (ws_size > 108 * MB) ? (ws_size - 108 * MB) : 0;

  // chunk geometry: heads-per-chunk HPC, row-chunk mr
  int HPC = 0, mr = 4096;
  if      (avail >= 256 * MB) HPC = 8;
  else if (avail >= 128 * MB) HPC = 4;
  else if (avail >=  64 * MB) HPC = 2;
  else if (avail >=  32 * MB) HPC = 1;
  else if (avail >=  16 * MB) { HPC = 1; mr = 2048; }
  const bool gemm_path = (HPC > 0);

  k_cvt<<<4096, 256, 0, stream>>>(x, xb, SEQ * NIN);
  k_cvt<<<10240, 256, 0, stream>>>(W, wb, HEADS * CPH * NIN);
  k_gemm_qkv<<<dim3(32, 80), 256, 0, stream>>>(xb, wb, b, Kx, Q2, Vd,
                                               gemm_path ? 1 : 0);
  k_stats<<<256, 256, 0, stream>>>(Kx, Q2, stat_m, stat_il);

  if (gemm_path) {
    const int nit = mr / 128;
    const int ldP = HPC * SEQ;
    // pick j-split so pwrite launches ~256 blocks
    int njs = 256 / (nit * HPC);
    if (njs < 1) njs = 1;
    while (64 % njs) njs >>= 1;        // njs must divide 64
    const int njt = 64 / njs;
    for (int i0 = 0; i0 < SEQ; i0 += mr) {
      for (int h0 = 0; h0 < HEADS; h0 += HPC) {
        k_pwrite<<<HPC * nit * njs, 256, 0, stream>>>(
            Kx, Q2, stat_m, stat_il, P, h0, i0, nit, njs, njt, ldP);
        k_pv_gemm<<<dim3(8, nit), 256, 0, stream>>>(
            P, Vd, out, ldP, h0 * SEQ, ldP / 32, i0, h0 != 0);
      }
    }
  } else {
    k_zero<<<4096, 256, 0, stream>>>((float4*)out);
    k_attn3<<<512, 512, 0, stream>>>(Kx, Q2, Vd, stat_m, stat_il, out);
  }
  k_ln<<<4096, 256, 0, stream>>>(out, lw, lb);
}

// Round 8
// 967.911 us; speedup vs baseline: 1.2087x; 1.2087x over previous
//
#include <hip/hip_runtime.h>

typedef __attribute__((ext_vector_type(8))) __bf16 bf16x8;
typedef __attribute__((ext_vector_type(4))) __bf16 bf16x4;
typedef __attribute__((ext_vector_type(4))) float f32x4;
typedef __attribute__((ext_vector_type(16))) float f32x16;

#define SEQ   4096
#define NIN   1024
#define DH    128
#define NOUTD 1024
#define HEADS 8
#define CPH   1280
#define L2E   1.44269504f
#define KTOT  32768   // concat K for PV GEMM = HEADS*SEQ

static __device__ inline f32x16 zero16() {
  f32x16 z;
#pragma unroll
  for (int r = 0; r < 16; ++r) z[r] = 0.f;
  return z;
}

static __device__ inline unsigned pk2(float a, float b) {
  unsigned short ua = __builtin_bit_cast(unsigned short, (__bf16)a);
  unsigned short ub = __builtin_bit_cast(unsigned short, (__bf16)b);
  return (unsigned)ua | ((unsigned)ub << 16);
}

// ---------------------------------------------------------------- f32 -> bf16
__global__ __launch_bounds__(256) void k_cvt(const float* __restrict__ src,
                                             __bf16* __restrict__ dst, int n) {
  int i = (blockIdx.x * 256 + threadIdx.x) * 4;
  if (i >= n) return;
  float4 v = *(const float4*)(src + i);
  bf16x4 o = { (__bf16)v.x, (__bf16)v.y, (__bf16)v.z, (__bf16)v.w };
  *(bf16x4*)(dst + i) = o;
}

// ---------------------------------------------------------------- zero d_out
__global__ __launch_bounds__(256) void k_zero(float4* __restrict__ p) {
  p[(size_t)blockIdx.x * 256 + threadIdx.x] = float4{0.f, 0.f, 0.f, 0.f};
}

// ------------------------------------------- GEMM: out = x @ W^T + b, scatter
// Kx[h][i][d] pre-scaled; Q2[h][dg][j][8].
// vmode=0: V2[h][J][e][8]   (fused-attn fallback layout)
// vmode=1: VT[e][h*SEQ + j] (B^T layout for the PV GEMM)
__global__ __launch_bounds__(256) void k_gemm_qkv(
    const __bf16* __restrict__ xb, const __bf16* __restrict__ wb,
    const float* __restrict__ bias,
    __bf16* __restrict__ Kx, __bf16* __restrict__ Q2, __bf16* __restrict__ Vd,
    int vmode)
{
  __shared__ __align__(16) __bf16 As[128 * 32];
  __shared__ __align__(16) __bf16 Bs[128 * 32];
  const int tid = threadIdx.x;
  const int w = tid >> 6, l = tid & 63;
  const int i0 = blockIdx.x * 128;
  const int n0 = blockIdx.y * 128;
  const int lrow = l & 15;
  const int lkb  = (l >> 4) * 16;
  const int soff = (w * 2) * 1024 + l * 16;

  f32x4 acc[4][4] = {};

  for (int kt = 0; kt < 32; ++kt) {
    __syncthreads();
#pragma unroll
    for (int q = 0; q < 2; ++q) {
      int off = soff + q * 1024;
      int row = off >> 6, kb = off & 63;
      const __bf16* ga = xb + (size_t)(i0 + row) * NIN + kt * 32 + (kb >> 1);
      const __bf16* gb = wb + (size_t)(n0 + row) * NIN + kt * 32 + (kb >> 1);
      __builtin_amdgcn_global_load_lds(
          (const __attribute__((address_space(1))) void*)ga,
          (__attribute__((address_space(3))) void*)((char*)As + (w * 2 + q) * 1024),
          16, 0, 0);
      __builtin_amdgcn_global_load_lds(
          (const __attribute__((address_space(1))) void*)gb,
          (__attribute__((address_space(3))) void*)((char*)Bs + (w * 2 + q) * 1024),
          16, 0, 0);
    }
    __syncthreads();
    bf16x8 af[4], bfr[4];
#pragma unroll
    for (int mi = 0; mi < 4; ++mi)
      af[mi] = *(const bf16x8*)((const char*)As + (((w >> 1) * 64 + mi * 16 + lrow) * 64) + lkb);
#pragma unroll
    for (int ni = 0; ni < 4; ++ni)
      bfr[ni] = *(const bf16x8*)((const char*)Bs + (((w & 1) * 64 + ni * 16 + lrow) * 64) + lkb);
#pragma unroll
    for (int mi = 0; mi < 4; ++mi)
#pragma unroll
      for (int ni = 0; ni < 4; ++ni)
        acc[mi][ni] = __builtin_amdgcn_mfma_f32_16x16x32_bf16(af[mi], bfr[ni], acc[mi][ni], 0, 0, 0);
  }

  const int iw = i0 + (w >> 1) * 64;
  const int nw = n0 + (w & 1) * 64;
  const int lhi = l >> 4;
#pragma unroll
  for (int ni = 0; ni < 4; ++ni) {
    int n = nw + ni * 16 + lrow;
    float bv = bias[n];
    int h = n / CPH;
    int c = n - h * CPH;
    if (c < 128) {
#pragma unroll
      for (int mi = 0; mi < 4; ++mi)
#pragma unroll
        for (int r = 0; r < 4; ++r) {
          int i = iw + mi * 16 + lhi * 4 + r;
          float v = acc[mi][ni][r] + bv;
          Kx[(((size_t)h * SEQ + i) << 7) + c] = (__bf16)(v * 0.08838834764831845f);
        }
    } else if (c < 256) {
      int d = c - 128;
      size_t qEl = ((size_t)(h * 16 + (d >> 3)) << 15) + (size_t)(d & 7);
#pragma unroll
      for (int mi = 0; mi < 4; ++mi)
#pragma unroll
        for (int r = 0; r < 4; ++r) {
          int j = iw + mi * 16 + lhi * 4 + r;
          Q2[qEl + ((size_t)j << 3)] = (__bf16)(acc[mi][ni][r] + bv);
        }
    } else {
      int e = c - 256;
#pragma unroll
      for (int mi = 0; mi < 4; ++mi) {
        int jb = iw + mi * 16 + lhi * 4;
        bf16x4 pk = { (__bf16)(acc[mi][ni][0] + bv), (__bf16)(acc[mi][ni][1] + bv),
                      (__bf16)(acc[mi][ni][2] + bv), (__bf16)(acc[mi][ni][3] + bv) };
        if (vmode) {
          *(bf16x4*)(Vd + (size_t)e * KTOT + (size_t)h * SEQ + jb) = pk;
        } else {
          int J = jb >> 3, js = jb & 7;
          *(bf16x4*)(Vd + (((size_t)(h * 512 + J)) << 13) + ((size_t)e << 3) + js) = pk;
        }
      }
    }
  }
}

// --------------------------------------------------------- pass A: softmax stats
// grid 256 = h(8) x itile(32 of 128 rows). 256 thr, 4 waves x 32 i-rows.
__global__ __launch_bounds__(256) void k_stats(
    const __bf16* __restrict__ Kx, const __bf16* __restrict__ Q2,
    float* __restrict__ stat_m, float* __restrict__ stat_il)
{
  __shared__ __align__(16) char Qb[2][16384];
  const int tid = threadIdx.x;
  const int w = tid >> 6, l = tid & 63;
  const int l31 = l & 31, hl = l >> 5;
  const int b = blockIdx.x;
  const int h = b >> 5;
  const int i_base = (b & 31) * 128;
  const __bf16* Kh = Kx + ((size_t)h * SEQ << 7);
  const char* q2b = (const char*)Q2 + ((size_t)h << 20);

  bf16x8 kf[8];
#pragma unroll
  for (int c = 0; c < 8; ++c)
    kf[c] = *(const bf16x8*)(Kh + (((size_t)(i_base + 32 * w + l31)) << 7) + c * 16 + hl * 8);

  float m_run = -1e30f, l_run = 0.f;

#pragma unroll
  for (int k = 0; k < 4; ++k) {
    int s = tid + k * 256;
    const char* src = q2b + ((size_t)(s >> 6) << 16) + (size_t)(s & 63) * 16;
    __builtin_amdgcn_global_load_lds(
        (const __attribute__((address_space(1))) void*)src,
        (__attribute__((address_space(3))) void*)(Qb[0] + s * 16), 16, 0, 0);
  }
  __syncthreads();

  for (int jt = 0; jt < 64; ++jt) {
    const int cur = jt & 1;
    if (jt < 63) {
      int j0n = (jt + 1) * 64;
#pragma unroll
      for (int k = 0; k < 4; ++k) {
        int s = tid + k * 256;
        const char* src = q2b + ((size_t)(s >> 6) << 16) + (size_t)(j0n + (s & 63)) * 16;
        __builtin_amdgcn_global_load_lds(
            (const __attribute__((address_space(1))) void*)src,
            (__attribute__((address_space(3))) void*)(Qb[cur ^ 1] + s * 16), 16, 0, 0);
      }
    }
    const char* qb = Qb[cur];

    f32x16 s0 = zero16(), s1 = zero16();
#pragma unroll
    for (int c = 0; c < 8; ++c) {
      bf16x8 a0 = *(const bf16x8*)(qb + (((2 * c + hl) * 64 + l31) << 4));
      bf16x8 a1 = *(const bf16x8*)(qb + (((2 * c + hl) * 64 + 32 + l31) << 4));
      s0 = __builtin_amdgcn_mfma_f32_32x32x16_bf16(a0, kf[c], s0, 0, 0, 0);
      s1 = __builtin_amdgcn_mfma_f32_32x32x16_bf16(a1, kf[c], s1, 0, 0, 0);
    }

    float pm = -1e30f;
#pragma unroll
    for (int r = 0; r < 16; ++r) pm = fmaxf(pm, fmaxf(s0[r], s1[r]));
    float mn = fmaxf(m_run, pm);
    l_run *= exp2f((m_run - mn) * L2E);
    float a = 0.f;
#pragma unroll
    for (int r = 0; r < 16; ++r)
      a += exp2f((s0[r] - mn) * L2E) + exp2f((s1[r] - mn) * L2E);
    l_run += a;
    m_run = mn;
    __syncthreads();
  }

  float mp = __shfl_xor(m_run, 32);
  float lp = __shfl_xor(l_run, 32);
  float mf = fmaxf(m_run, mp);
  float lf = l_run * exp2f((m_run - mf) * L2E) + lp * exp2f((mp - mf) * L2E);
  if (hl == 0) {
    int i = i_base + 32 * w + l31;
    stat_m[h * SEQ + i] = mf;
    stat_il[h * SEQ + i] = 1.0f / lf;
  }
}

// --------------------------------------------------------- P~ write pass (chunked)
// Recompute S for heads [h0, h0+nh), rows [i0, i0+nit*128), j-slice per block.
// P chunk layout: P[i_loc][hh*SEQ + j], row stride ldP = nh*SEQ.
// grid = nh * nit * njs;  b -> js (fastest), itile, hh.
__global__ __launch_bounds__(256) void k_pwrite(
    const __bf16* __restrict__ Kx, const __bf16* __restrict__ Q2,
    const float* __restrict__ stat_m, const float* __restrict__ stat_il,
    __bf16* __restrict__ P, int h0, int i0, int nit, int njs, int njt, int ldP)
{
  __shared__ __align__(16) char Qb[2][16384];
  const int tid = threadIdx.x;
  const int w = tid >> 6, l = tid & 63;
  const int l31 = l & 31, hl = l >> 5;

  const int bb = blockIdx.x;
  const int js = bb % njs;
  const int rem = bb / njs;
  const int itile = rem % nit;
  const int hh = rem / nit;
  const int h = h0 + hh;
  const int jt0 = js * njt;

  const __bf16* Kh = Kx + ((size_t)h * SEQ << 7);
  const char* q2b = (const char*)Q2 + ((size_t)h << 20);

  const int i_loc = itile * 128 + 32 * w + l31;
  const int i_gl = i0 + i_loc;
  const float m_i = stat_m[h * SEQ + i_gl];
  const float il_i = stat_il[h * SEQ + i_gl];
  __bf16* prow = P + (size_t)i_loc * ldP + (size_t)hh * SEQ;

  bf16x8 kf[8];
#pragma unroll
  for (int c = 0; c < 8; ++c)
    kf[c] = *(const bf16x8*)(Kh + (((size_t)i_gl) << 7) + c * 16 + hl * 8);

#pragma unroll
  for (int k = 0; k < 4; ++k) {
    int s = tid + k * 256;
    const char* src = q2b + ((size_t)(s >> 6) << 16) + (size_t)(jt0 * 64 + (s & 63)) * 16;
    __builtin_amdgcn_global_load_lds(
        (const __attribute__((address_space(1))) void*)src,
        (__attribute__((address_space(3))) void*)(Qb[0] + s * 16), 16, 0, 0);
  }
  __syncthreads();

  for (int t = 0; t < njt; ++t) {
    const int jt = jt0 + t;
    const int cur = t & 1;
    if (t < njt - 1) {
      int j0n = (jt + 1) * 64;
#pragma unroll
      for (int k = 0; k < 4; ++k) {
        int s = tid + k * 256;
        const char* src = q2b + ((size_t)(s >> 6) << 16) + (size_t)(j0n + (s & 63)) * 16;
        __builtin_amdgcn_global_load_lds(
            (const __attribute__((address_space(1))) void*)src,
            (__attribute__((address_space(3))) void*)(Qb[cur ^ 1] + s * 16), 16, 0, 0);
      }
    }
    const char* qb = Qb[cur];

    f32x16 s0 = zero16(), s1 = zero16();
#pragma unroll
    for (int c = 0; c < 8; ++c) {
      bf16x8 a0 = *(const bf16x8*)(qb + (((2 * c + hl) * 64 + l31) << 4));
      bf16x8 a1 = *(const bf16x8*)(qb + (((2 * c + hl) * 64 + 32 + l31) << 4));
      s0 = __builtin_amdgcn_mfma_f32_32x32x16_bf16(a0, kf[c], s0, 0, 0, 0);
      s1 = __builtin_amdgcn_mfma_f32_32x32x16_bf16(a1, kf[c], s1, 0, 0, 0);
    }

    // transpose to row-contiguous j, fold il, store 16B per lane
#pragma unroll
    for (int c2 = 0; c2 < 4; ++c2) {
      const f32x16& sv = (c2 >> 1) ? s1 : s0;
      const int base = (c2 & 1) * 8;
      float e0 = il_i * exp2f((sv[base + 0] - m_i) * L2E);
      float e1 = il_i * exp2f((sv[base + 1] - m_i) * L2E);
      float e2 = il_i * exp2f((sv[base + 2] - m_i) * L2E);
      float e3 = il_i * exp2f((sv[base + 3] - m_i) * L2E);
      float e4 = il_i * exp2f((sv[base + 4] - m_i) * L2E);
      float e5 = il_i * exp2f((sv[base + 5] - m_i) * L2E);
      float e6 = il_i * exp2f((sv[base + 6] - m_i) * L2E);
      float e7 = il_i * exp2f((sv[base + 7] - m_i) * L2E);
      unsigned WA0 = pk2(e0, e1), WA1 = pk2(e2, e3);
      unsigned WB0 = pk2(e4, e5), WB1 = pk2(e6, e7);
      unsigned send0 = hl ? WA0 : WB0;
      unsigned send1 = hl ? WA1 : WB1;
      unsigned r0 = (unsigned)__shfl_xor((int)send0, 32);
      unsigned r1 = (unsigned)__shfl_xor((int)send1, 32);
      int4 qd;
      qd.x = (int)(hl ? r0 : WA0);
      qd.y = (int)(hl ? r1 : WA1);
      qd.z = (int)(hl ? WB0 : r0);
      qd.w = (int)(hl ? WB1 : r1);
      *(int4*)(prow + jt * 64 + 16 * c2 + 8 * hl) = qd;
    }
    __syncthreads();
  }
}

// --------------------------------------------------------- PV dense GEMM (chunked, K-split)
// out[i0+.., :] += P_chunk[mr x ldP] @ VT[:, k0 + ks-slice]^T  (atomic accumulate)
// grid (8 n, nit i, 4 ks); each block does kiters = ldP/128 K-steps.
__global__ __launch_bounds__(256) void k_pv_gemm(
    const __bf16* __restrict__ P, const __bf16* __restrict__ VT,
    float* __restrict__ out, int ldP, int k0base, int kiters, int i0)
{
  __shared__ __align__(16) __bf16 As[128 * 32];
  __shared__ __align__(16) __bf16 Bs[128 * 32];
  const int tid = threadIdx.x;
  const int w = tid >> 6, l = tid & 63;
  const int iblk = blockIdx.y * 128;
  const int n0 = blockIdx.x * 128;
  const int kloc0 = blockIdx.z * kiters * 32;           // local k offset in P chunk
  const int lrow = l & 15;
  const int lkb  = (l >> 4) * 16;
  const int soff = (w * 2) * 1024 + l * 16;

  f32x4 acc[4][4] = {};

  for (int kt = 0; kt < kiters; ++kt) {
    __syncthreads();
#pragma unroll
    for (int q = 0; q < 2; ++q) {
      int off = soff + q * 1024;
      int row = off >> 6, kb = off & 63;
      const __bf16* ga = P  + (size_t)(iblk + row) * ldP + kloc0 + kt * 32 + (kb >> 1);
      const __bf16* gb = VT + (size_t)(n0 + row) * KTOT + k0base + kloc0 + kt * 32 + (kb >> 1);
      __builtin_amdgcn_global_load_lds(
          (const __attribute__((address_space(1))) void*)ga,
          (__attribute__((address_space(3))) void*)((char*)As + (w * 2 + q) * 1024),
          16, 0, 0);
      __builtin_amdgcn_global_load_lds(
          (const __attribute__((address_space(1))) void*)gb,
          (__attribute__((address_space(3))) void*)((char*)Bs + (w * 2 + q) * 1024),
          16, 0, 0);
    }
    __syncthreads();
    bf16x8 af[4], bfr[4];
#pragma unroll
    for (int mi = 0; mi < 4; ++mi)
      af[mi] = *(const bf16x8*)((const char*)As + (((w >> 1) * 64 + mi * 16 + lrow) * 64) + lkb);
#pragma unroll
    for (int ni = 0; ni < 4; ++ni)
      bfr[ni] = *(const bf16x8*)((const char*)Bs + (((w & 1) * 64 + ni * 16 + lrow) * 64) + lkb);
#pragma unroll
    for (int mi = 0; mi < 4; ++mi)
#pragma unroll
      for (int ni = 0; ni < 4; ++ni)
        acc[mi][ni] = __builtin_amdgcn_mfma_f32_16x16x32_bf16(af[mi], bfr[ni], acc[mi][ni], 0, 0, 0);
  }

  const int iw = i0 + iblk + (w >> 1) * 64;
  const int nw = n0 + (w & 1) * 64;
  const int lhi = l >> 4;
#pragma unroll
  for (int ni = 0; ni < 4; ++ni) {
    int e = nw + ni * 16 + lrow;
#pragma unroll
    for (int mi = 0; mi < 4; ++mi)
#pragma unroll
      for (int r = 0; r < 4; ++r) {
        int i = iw + mi * 16 + lhi * 4 + r;
        atomicAdd(out + ((size_t)i << 10) + e, acc[mi][ni][r]);
      }
  }
}

// --------------------------------------------------------- fallback fused attn
__global__ __launch_bounds__(512, 2) void k_attn3(
    const __bf16* __restrict__ Kx, const __bf16* __restrict__ Q2,
    const __bf16* __restrict__ V2, const float* __restrict__ stat_m,
    const float* __restrict__ stat_il, float* __restrict__ out)
{
  __shared__ __align__(16) char Qb[2][8192];
  __shared__ __align__(16) char Vb[2][16384];
  __shared__ float s_linv[256];

  const int tid = threadIdx.x;
  const int w = tid >> 6, l = tid & 63;
  const int l31 = l & 31, hl = l >> 5;
  const int islot = w & 3, eslot = w >> 2;

  const int b = blockIdx.x;
  const int et = b & 3;
  const int h = ((b >> 2) & 1) + 2 * (b >> 7);
  const int it = (b >> 3) & 15;
  const int i_base = it * 256, e_base = et * 256;

  const __bf16* Kh = Kx + ((size_t)h * SEQ << 7);
  const char* q2b = (const char*)Q2 + ((size_t)h << 20);
  const char* v2b = (const char*)V2 + ((size_t)(h * 512) << 14) + ((size_t)e_base << 4);

  if (tid < 256) s_linv[tid] = stat_il[h * SEQ + i_base + tid];
  const int iw0 = i_base + islot * 64;
  const float m0 = stat_m[h * SEQ + iw0 + l31];
  const float m1 = stat_m[h * SEQ + iw0 + 32 + l31];

  bf16x8 kf[2][8];
#pragma unroll
  for (int ig = 0; ig < 2; ++ig)
#pragma unroll
    for (int c = 0; c < 8; ++c)
      kf[ig][c] = *(const bf16x8*)(Kh + (((size_t)(iw0 + ig * 32 + l31)) << 7) + c * 16 + hl * 8);

  f32x16 acc[2][4];
#pragma unroll
  for (int ig = 0; ig < 2; ++ig)
#pragma unroll
    for (int n = 0; n < 4; ++n) acc[ig][n] = zero16();

  {
    const char* srcQ = q2b + ((size_t)(tid >> 5) << 16) + (size_t)(tid & 31) * 16;
    __builtin_amdgcn_global_load_lds(
        (const __attribute__((address_space(1))) void*)srcQ,
        (__attribute__((address_space(3))) void*)(Qb[0] + tid * 16), 16, 0, 0);
#pragma unroll
    for (int k = 0; k < 2; ++k) {
      int s = tid + k * 512;
      const char* srcV = v2b + ((size_t)(s >> 8) << 14) + (size_t)(s & 255) * 16;
      __builtin_amdgcn_global_load_lds(
          (const __attribute__((address_space(1))) void*)srcV,
          (__attribute__((address_space(3))) void*)(Vb[0] + s * 16), 16, 0, 0);
    }
  }
  __syncthreads();

  for (int jt = 0; jt < 128; ++jt) {
    const int cur = jt & 1;
    if (jt < 127) {
      const int j0n = (jt + 1) * 32;
      const char* srcQ = q2b + ((size_t)(tid >> 5) << 16) + (size_t)(j0n + (tid & 31)) * 16;
      __builtin_amdgcn_global_load_lds(
          (const __attribute__((address_space(1))) void*)srcQ,
          (__attribute__((address_space(3))) void*)(Qb[cur ^ 1] + tid * 16), 16, 0, 0);
#pragma unroll
      for (int k = 0; k < 2; ++k) {
        int s = tid + k * 512;
        const char* srcV = v2b + ((size_t)((jt + 1) * 4 + (s >> 8)) << 14) + (size_t)(s & 255) * 16;
        __builtin_amdgcn_global_load_lds(
            (const __attribute__((address_space(1))) void*)srcV,
            (__attribute__((address_space(3))) void*)(Vb[cur ^ 1] + s * 16), 16, 0, 0);
      }
    }
    const char* qb = Qb[cur];
    const char* vb = Vb[cur];

    f32x16 s0 = zero16(), s1 = zero16();
#pragma unroll
    for (int c = 0; c < 8; ++c) {
      bf16x8 a0 = *(const bf16x8*)(qb + (((2 * c + hl) * 32 + l31) << 4));
      s0 = __builtin_amdgcn_mfma_f32_32x32x16_bf16(a0, kf[0][c], s0, 0, 0, 0);
      s1 = __builtin_amdgcn_mfma_f32_32x32x16_bf16(a0, kf[1][c], s1, 0, 0, 0);
    }

    bf16x8 pf[2][2];
#pragma unroll
    for (int ig = 0; ig < 2; ++ig) {
      const f32x16& sv = ig ? s1 : s0;
      const float mi = ig ? m1 : m0;
#pragma unroll
      for (int c2 = 0; c2 < 2; ++c2) {
        const int base = 8 * c2;
        float e0 = exp2f((sv[base + 0] - mi) * L2E);
        float e1 = exp2f((sv[base + 1] - mi) * L2E);
        float e2 = exp2f((sv[base + 2] - mi) * L2E);
        float e3 = exp2f((sv[base + 3] - mi) * L2E);
        float e4 = exp2f((sv[base + 4] - mi) * L2E);
        float e5 = exp2f((sv[base + 5] - mi) * L2E);
        float e6 = exp2f((sv[base + 6] - mi) * L2E);
        float e7 = exp2f((sv[base + 7] - mi) * L2E);
        unsigned WA0 = pk2(e0, e1), WA1 = pk2(e2, e3);
        unsigned WB0 = pk2(e4, e5), WB1 = pk2(e6, e7);
        unsigned send0 = hl ? WA0 : WB0;
        unsigned send1 = hl ? WA1 : WB1;
        unsigned r0 = (unsigned)__shfl_xor((int)send0, 32);
        unsigned r1 = (unsigned)__shfl_xor((int)send1, 32);
        int4 qd;
        qd.x = (int)(hl ? r0 : WA0);
        qd.y = (int)(hl ? r1 : WA1);
        qd.z = (int)(hl ? WB0 : r0);
        qd.w = (int)(hl ? WB1 : r1);
        pf[ig][c2] = __builtin_bit_cast(bf16x8, qd);
      }
    }

#pragma unroll
    for (int c2 = 0; c2 < 2; ++c2)
#pragma unroll
      for (int n = 0; n < 4; ++n) {
        bf16x8 bv = *(const bf16x8*)(vb + (((2 * c2 + hl) * 256 + eslot * 128 + 32 * n + l31) << 4));
        acc[0][n] = __builtin_amdgcn_mfma_f32_32x32x16_bf16(pf[0][c2], bv, acc[0][n], 0, 0, 0);
        acc[1][n] = __builtin_amdgcn_mfma_f32_32x32x16_bf16(pf[1][c2], bv, acc[1][n], 0, 0, 0);
      }
    __syncthreads();
  }

#pragma unroll
  for (int ig = 0; ig < 2; ++ig)
#pragma unroll
    for (int n = 0; n < 4; ++n) {
      const int e = e_base + eslot * 128 + 32 * n + l31;
#pragma unroll
      for (int r = 0; r < 16; ++r) {
        int row = (r & 3) + 8 * (r >> 2) + 4 * hl;
        int iloc = islot * 64 + ig * 32 + row;
        float v = acc[ig][n][r] * s_linv[iloc];
        atomicAdd(out + (((size_t)(i_base + iloc)) << 10) + e, v);
      }
    }
}

// ---------------------------------------------------------------- LayerNorm
__global__ __launch_bounds__(256) void k_ln(float* __restrict__ io,
                                            const float* __restrict__ lw,
                                            const float* __restrict__ lb) {
  const int i = blockIdx.x, t = threadIdx.x;
  const int w = t >> 6, l = t & 63;
  float4 v = *(const float4*)(io + ((size_t)i << 10) + t * 4);
  float s = v.x + v.y + v.z + v.w;
  float q = v.x * v.x + v.y * v.y + v.z * v.z + v.w * v.w;
#pragma unroll
  for (int d = 1; d < 64; d <<= 1) {
    s += __shfl_xor(s, d);
    q += __shfl_xor(q, d);
  }
  __shared__ float red[4][2];
  if (l == 0) { red[w][0] = s; red[w][1] = q; }
  __syncthreads();
  s = red[0][0] + red[1][0] + red[2][0] + red[3][0];
  q = red[0][1] + red[1][1] + red[2][1] + red[3][1];
  float mean = s * (1.0f / 1024.0f);
  float var = q * (1.0f / 1024.0f) - mean * mean;
  float rstd = rsqrtf(var + 1e-5f);
  float4 gw = *(const float4*)(lw + t * 4);
  float4 gb = *(const float4*)(lb + t * 4);
  float4 ov;
  ov.x = (v.x - mean) * rstd * gw.x + gb.x;
  ov.y = (v.y - mean) * rstd * gw.y + gb.y;
  ov.z = (v.z - mean) * rstd * gw.z + gb.z;
  ov.w = (v.w - mean) * rstd * gw.w + gb.w;
  *(float4*)(io + ((size_t)i << 10) + t * 4) = ov;
}

// ---------------------------------------------------------------- launch
extern "C" void kernel_launch(void* const* d_in, const int* in_sizes, int n_in,
                              void* d_out, int out_size, void* d_ws, size_t ws_size,
                              hipStream_t stream) {
  (void)in_sizes; (void)n_in; (void)out_size;
  const float* x  = (const float*)d_in[0];
  const float* W  = (const float*)d_in[1];
  const float* b  = (const float*)d_in[2];
  const float* lw = (const float*)d_in[3];
  const float* lb = (const float*)d_in[4];
  float* out = (float*)d_out;
  char* ws = (char*)d_ws;

  __bf16* xb = (__bf16*)ws;                                    //  8 MB (dead after GEMM)
  __bf16* wb = (__bf16*)(ws + (size_t)8  * 1024 * 1024);       // 20 MB
  __bf16* Kx = (__bf16*)(ws + (size_t)28 * 1024 * 1024);       //  8 MB
  __bf16* Q2 = (__bf16*)(ws + (size_t)36 * 1024 * 1024);       //  8 MB
  __bf16* Vd = (__bf16*)(ws + (size_t)44 * 1024 * 1024);       // 64 MB (V2 or VT)
  __bf16* P  = (__bf16*)(ws + (size_t)108 * 1024 * 1024);      // chunk buffer
  float* stat_m  = (float*)ws;                                 // reuse xb after GEMM
  float* stat_il = (float*)(ws + (size_t)128 * 1024);

  const size_t MB = (size_t)1024 * 1024;
  const size_t avail = (ws_size > 108 * MB) ? (ws_size - 108 * MB) : 0;

  // chunk geometry: heads-per-chunk HPC, row-chunk mr
  int HPC = 0, mr = 4096;
  if      (avail >= 256 * MB) HPC = 8;
  else if (avail >= 128 * MB) HPC = 4;
  else if (avail >=  64 * MB) HPC = 2;
  else if (avail >=  32 * MB) HPC = 1;
  else if (avail >=  16 * MB) { HPC = 1; mr = 2048; }
  const bool gemm_path = (HPC > 0);

  k_cvt<<<4096, 256, 0, stream>>>(x, xb, SEQ * NIN);
  k_cvt<<<10240, 256, 0, stream>>>(W, wb, HEADS * CPH * NIN);
  k_gemm_qkv<<<dim3(32, 80), 256, 0, stream>>>(xb, wb, b, Kx, Q2, Vd,
                                               gemm_path ? 1 : 0);
  k_stats<<<256, 256, 0, stream>>>(Kx, Q2, stat_m, stat_il);
  k_zero<<<4096, 256, 0, stream>>>((float4*)out);

  if (gemm_path) {
    const int nit = mr / 128;
    const int ldP = HPC * SEQ;
    // pick j-split so pwrite launches ~256 blocks
    int njs = 256 / (nit * HPC);
    if (njs < 1) njs = 1;
    while (64 % njs) njs >>= 1;        // njs must divide 64
    const int njt = 64 / njs;
    const int kiters = ldP / 128;      // per K-split block (4 splits)
    for (int i0 = 0; i0 < SEQ; i0 += mr) {
      for (int h0 = 0; h0 < HEADS; h0 += HPC) {
        k_pwrite<<<HPC * nit * njs, 256, 0, stream>>>(
            Kx, Q2, stat_m, stat_il, P, h0, i0, nit, njs, njt, ldP);
        k_pv_gemm<<<dim3(8, nit, 4), 256, 0, stream>>>(
            P, Vd, out, ldP, h0 * SEQ, kiters, i0);
      }
    }
  } else {
    k_attn3<<<512, 512, 0, stream>>>(Kx, Q2, Vd, stat_m, stat_il, out);
  }
  k_ln<<<4096, 256, 0, stream>>>(out, lw, lb);
}